// Round 3
// baseline (14854.477 us; speedup 1.0000x reference)
//
#include <hip/hip_runtime.h>
#include <math.h>

#define BB 256
#define TT 512
#define DD 256
#define HH 512
#define SS 8
#define G4H 2048

__device__ __forceinline__ float sigm(float x) { return 1.f / (1.f + __expf(-x)); }

// ---------------- prep kernels ----------------

// W_big[n][j] = sum_d W_ih[n][d]*W_lin[d][j] + W_hh[n][j]   (2048x512, K=256)
__global__ __launch_bounds__(256) void prep_wbig(
    const float* __restrict__ W_ih, const float* __restrict__ W_hh,
    const float* __restrict__ W_lin, float* __restrict__ W_big)
{
  __shared__ float As[64][20];
  __shared__ float Bs[16][68];
  const int n0 = blockIdx.x * 64;
  const int j0 = blockIdx.y * 64;
  const int tid = threadIdx.x;
  const int tn = tid >> 4, tj = tid & 15;
  float acc[4][4] = {};
  for (int k0 = 0; k0 < DD; k0 += 16) {
    { int r = tid >> 2, c = (tid & 3) * 4;
      *(float4*)&As[r][c] = *(const float4*)&W_ih[(size_t)(n0 + r) * DD + k0 + c]; }
    { int r = tid >> 4, c = (tid & 15) * 4;
      *(float4*)&Bs[r][c] = *(const float4*)&W_lin[(size_t)(k0 + r) * HH + j0 + c]; }
    __syncthreads();
    #pragma unroll
    for (int k = 0; k < 16; ++k) {
      float a[4], bv[4];
      #pragma unroll
      for (int i = 0; i < 4; ++i) a[i] = As[tn*4+i][k];
      #pragma unroll
      for (int m = 0; m < 4; ++m) bv[m] = Bs[k][tj*4+m];
      #pragma unroll
      for (int i = 0; i < 4; ++i)
        #pragma unroll
        for (int m = 0; m < 4; ++m)
          acc[i][m] = fmaf(a[i], bv[m], acc[i][m]);
    }
    __syncthreads();
  }
  #pragma unroll
  for (int i = 0; i < 4; ++i) {
    int n = n0 + tn*4 + i;
    #pragma unroll
    for (int m = 0; m < 4; ++m) {
      int j = j0 + tj*4 + m;
      W_big[(size_t)n*HH + j] = acc[i][m] + W_hh[(size_t)n*HH + j];
    }
  }
}

// bias0[n] = b_ih+b_hh ; bias1[n] = bias0[n] + dot(W_ih[n,:], b_lin)
__global__ void prep_bias(const float* __restrict__ b_ih, const float* __restrict__ b_hh,
                          const float* __restrict__ W_ih, const float* __restrict__ b_lin,
                          float* __restrict__ bias0, float* __restrict__ bias1)
{
  int n = blockIdx.x * 256 + threadIdx.x;   // grid 8
  float s = b_ih[n] + b_hh[n];
  float d = 0.f;
  for (int k = 0; k < DD; ++k) d = fmaf(W_ih[(size_t)n*DD + k], b_lin[k], d);
  bias0[n] = s;
  bias1[n] = s + d;
}

// init skip buffers (S x B x H) from h0/c0, and cbuf = c0
__global__ void prep_init(const float* __restrict__ h0, const float* __restrict__ c0,
                          float* __restrict__ bh, float* __restrict__ bc,
                          float* __restrict__ cbuf)
{
  int e = blockIdx.x * 256 + threadIdx.x;   // grid 4096 -> 1M elems
  int r = e & (BB*HH - 1);
  bh[e] = h0[r];
  bc[e] = c0[r];
  if (e < BB*HH) cbuf[e] = c0[e];
}

// ---------------- per-step kernel ----------------

// Tile GEMM: acc[2][4] += A[b0+ty*2+i][:] . W[row(p=m*16+tx)][:]
// row(p) = row0 + (p>>4)*gstride + (p&15)
__device__ __forceinline__ void gemm_acc(
    float acc[2][4],
    const float* __restrict__ A, int lda, int b0,
    const float* __restrict__ W, int ldw, int row0, int gstride, int K,
    int tid, int tx, int ty,
    float (*As)[36], float (*Ws)[36])
{
  const int ar = tid >> 3;           // 0..31
  const int ac = (tid & 7) * 4;      // 0,4,..,28
  for (int k0 = 0; k0 < K; k0 += 32) {
    *(float4*)&As[ar][ac] = *(const float4*)&A[(size_t)(b0 + ar) * lda + k0 + ac];
    {
      int p = ar;
      int row = row0 + (p >> 4) * gstride + (p & 15);
      *(float4*)&Ws[p][ac] = *(const float4*)&W[(size_t)row * ldw + k0 + ac];
      p = ar + 32;
      row = row0 + (p >> 4) * gstride + (p & 15);
      *(float4*)&Ws[p][ac] = *(const float4*)&W[(size_t)row * ldw + k0 + ac];
    }
    __syncthreads();
    #pragma unroll
    for (int k = 0; k < 32; k += 4) {
      float4 a0 = *(const float4*)&As[ty*2+0][k];
      float4 a1 = *(const float4*)&As[ty*2+1][k];
      #pragma unroll
      for (int m = 0; m < 4; ++m) {
        float4 w = *(const float4*)&Ws[m*16+tx][k];
        acc[0][m] = fmaf(a0.x, w.x, acc[0][m]);
        acc[0][m] = fmaf(a0.y, w.y, acc[0][m]);
        acc[0][m] = fmaf(a0.z, w.z, acc[0][m]);
        acc[0][m] = fmaf(a0.w, w.w, acc[0][m]);
        acc[1][m] = fmaf(a1.x, w.x, acc[1][m]);
        acc[1][m] = fmaf(a1.y, w.y, acc[1][m]);
        acc[1][m] = fmaf(a1.z, w.z, acc[1][m]);
        acc[1][m] = fmaf(a1.w, w.w, acc[1][m]);
      }
    }
    __syncthreads();
  }
}

// One launch per time step t in [0, TT]:
//   blocks 0..255  : gates GEMM + fused LSTM/skip elementwise for step t (if t<TT)
//   blocks 256..287: out GEMM for step t-1 (if t>=1)
// Stream ordering between launches provides the recurrence dependency.
__global__ __launch_bounds__(256, 2) void lstm_step(
    const float* __restrict__ x0,     // _input (only t=0 slice used), lda = TT*DD
    const float* __restrict__ h0,
    const float* __restrict__ W_ih,   // 2048x256
    const float* __restrict__ W_hh,   // 2048x512
    const float* __restrict__ W_lin,  // 256x512
    const float* __restrict__ b_lin,  // 256
    const int* __restrict__ w1,
    const int* __restrict__ w2,
    const float* __restrict__ W_big,  // 2048x512
    const float* __restrict__ bias0,
    const float* __restrict__ bias1,
    float* __restrict__ hbuf,         // 2 x B*H (ping-pong comb_h)
    float* __restrict__ cbuf,         // B*H (comb_c)
    float* __restrict__ bh,           // S x B*H
    float* __restrict__ bc,           // S x B*H
    float* __restrict__ out,          // B*T*D | B*H (h_fin) | B*H (c_fin)
    int t)
{
  __shared__ float As[32][36];
  __shared__ float Ws[64][36];
  const int tid = threadIdx.x;
  const int tx = tid & 15;
  const int ty = tid >> 4;
  const int blk = blockIdx.x;

  if (blk < 256) {
    if (t < TT) {
      // gates blocks: 8 b-tiles x 32 j-tiles
      const int gb0 = (blk >> 5) * 32;
      const int gj0 = (blk & 31) * 16;
      float acc[2][4] = {{0.f,0.f,0.f,0.f},{0.f,0.f,0.f,0.f}};
      if (t == 0) {
        gemm_acc(acc, x0, TT*DD, gb0, W_ih, DD, gj0, HH, DD, tid, tx, ty, As, Ws);
        gemm_acc(acc, h0, HH,    gb0, W_hh, HH, gj0, HH, HH, tid, tx, ty, As, Ws);
      } else {
        gemm_acc(acc, hbuf + ((t-1)&1)*(BB*HH), HH, gb0, W_big, HH, gj0, HH, HH,
                 tid, tx, ty, As, Ws);
      }
      // fused elementwise LSTM + skip combine
      const float* bias = (t == 0) ? bias0 : bias1;
      const int j = gj0 + tx;
      const float bi = bias[0*HH + j];
      const float bf = bias[1*HH + j];
      const float bg = bias[2*HH + j];
      const float bo = bias[3*HH + j];
      const float a1 = (float)w1[t];
      const float a2 = (float)w2[t];
      const float nrm = 1.f / (a1 + a2);
      const int pos = t & (SS - 1);
      float* hb_out = hbuf + (t & 1) * (BB*HH);
      #pragma unroll
      for (int i = 0; i < 2; ++i) {
        const int b = gb0 + ty*2 + i;
        const int idx = b*HH + j;
        float gi = acc[i][0] + bi;
        float gf = acc[i][1] + bf;
        float gg = acc[i][2] + bg;
        float go = acc[i][3] + bo;
        float si = sigm(gi);
        float sf = sigm(gf);
        float so = sigm(go);
        float tg = tanhf(gg);
        float cold = cbuf[idx];
        float cnew = fmaf(sf, cold, si * tg);
        float hnew = so * tanhf(cnew);
        const int bidx = pos*(BB*HH) + idx;
        float sh = bh[bidx], sc = bc[bidx];
        bh[bidx] = hnew;
        bc[bidx] = cnew;
        float ch = (a1*hnew + a2*tanhf(sh)) * nrm;
        float cc = (a1*cnew + a2*tanhf(sc)) * nrm;
        hb_out[idx] = ch;
        cbuf[idx]   = cc;
        if (t == TT-1) {
          out[(size_t)BB*TT*DD + idx] = ch;           // h_fin
          out[(size_t)BB*TT*DD + BB*HH + idx] = cc;   // c_fin
        }
      }
    }
  } else {
    if (t >= 1) {
      // out blocks: out_{t-1} = comb_h_{t-1} @ W_lin^T + b_lin
      const int ob  = blk - 256;
      const int ob0 = (ob >> 2) * 32;
      const int od0 = (ob & 3) * 64;
      float acc[2][4] = {{0.f,0.f,0.f,0.f},{0.f,0.f,0.f,0.f}};
      gemm_acc(acc, hbuf + ((t-1)&1)*(BB*HH), HH, ob0, W_lin, HH, od0, 16, HH,
               tid, tx, ty, As, Ws);
      #pragma unroll
      for (int i = 0; i < 2; ++i) {
        const int b = ob0 + ty*2 + i;
        #pragma unroll
        for (int m = 0; m < 4; ++m) {
          const int d = od0 + m*16 + tx;
          out[(size_t)b*TT*DD + (size_t)(t-1)*DD + d] = acc[i][m] + b_lin[d];
        }
      }
    }
  }
}

// ---------------- host launch ----------------

extern "C" void kernel_launch(void* const* d_in, const int* in_sizes, int n_in,
                              void* d_out, int out_size, void* d_ws, size_t ws_size,
                              hipStream_t stream)
{
  const float* x0    = (const float*)d_in[0];
  const float* h0    = (const float*)d_in[1];
  const float* c0    = (const float*)d_in[2];
  const float* W_ih  = (const float*)d_in[3];
  const float* W_hh  = (const float*)d_in[4];
  const float* b_ih  = (const float*)d_in[5];
  const float* b_hh  = (const float*)d_in[6];
  const float* W_lin = (const float*)d_in[7];
  const float* b_lin = (const float*)d_in[8];
  const int*   w1    = (const int*)d_in[9];
  const int*   w2    = (const int*)d_in[10];

  float* ws = (float*)d_ws;
  size_t off = 0;
  float* W_big = ws + off; off += (size_t)G4H * HH;       // 4 MB
  float* bias0 = ws + off; off += G4H;
  float* bias1 = ws + off; off += G4H;
  float* hbuf  = ws + off; off += (size_t)2 * BB * HH;    // ping-pong comb_h
  float* cbuf  = ws + off; off += (size_t)BB * HH;
  float* bh    = ws + off; off += (size_t)SS * BB * HH;   // 4 MB
  float* bc    = ws + off; off += (size_t)SS * BB * HH;   // 4 MB
  float* outp  = (float*)d_out;

  hipLaunchKernelGGL(prep_wbig, dim3(32, 8), dim3(256), 0, stream, W_ih, W_hh, W_lin, W_big);
  hipLaunchKernelGGL(prep_bias, dim3(8), dim3(256), 0, stream, b_ih, b_hh, W_ih, b_lin, bias0, bias1);
  hipLaunchKernelGGL(prep_init, dim3(4096), dim3(256), 0, stream, h0, c0, bh, bc, cbuf);

  for (int t = 0; t <= TT; ++t) {
    hipLaunchKernelGGL(lstm_step, dim3(288), dim3(256), 0, stream,
                       x0, h0, W_ih, W_hh, W_lin, b_lin, w1, w2,
                       W_big, bias0, bias1, hbuf, cbuf, bh, bc, outp, t);
  }
}

// Round 4
// 12688.582 us; speedup vs baseline: 1.1707x; 1.1707x over previous
//
#include <hip/hip_runtime.h>
#include <math.h>

#define BB 256
#define TT 512
#define DD 256
#define HH 512
#define SS 8
#define G4H 2048
#define BH (BB*HH)          // 131072
#define GRP_ROWS 32
#define NGRP 8
#define BLK_PER_GRP 18      // 16 gates + 2 out
#define OUT_BASE ((size_t)BB*TT*DD)   // 33554432

typedef _Float16 f16;
typedef __attribute__((ext_vector_type(8)))  _Float16 f16x8;
typedef __attribute__((ext_vector_type(16))) float    f32x16;

__device__ __forceinline__ float sigm(float x) { return 1.f / (1.f + __expf(-x)); }
__device__ __forceinline__ float ftanh(float x) {
  x = fminf(15.f, fmaxf(-15.f, x));
  float e = __expf(-2.f * x);
  return (1.f - e) / (1.f + e);
}

// ---------------- prep kernels ----------------

// W_big[n][j] = sum_d W_ih[n][d]*W_lin[d][j] + W_hh[n][j]  -> fp16 (2048x512)
__global__ __launch_bounds__(256) void prep_wbig16(
    const float* __restrict__ W_ih, const float* __restrict__ W_hh,
    const float* __restrict__ W_lin, f16* __restrict__ Wbig16)
{
  __shared__ float As[64][20];
  __shared__ float Bs[16][68];
  const int n0 = blockIdx.x * 64;
  const int j0 = blockIdx.y * 64;
  const int tid = threadIdx.x;
  const int tn = tid >> 4, tj = tid & 15;
  float acc[4][4] = {};
  for (int k0 = 0; k0 < DD; k0 += 16) {
    { int r = tid >> 2, c = (tid & 3) * 4;
      *(float4*)&As[r][c] = *(const float4*)&W_ih[(size_t)(n0 + r) * DD + k0 + c]; }
    { int r = tid >> 4, c = (tid & 15) * 4;
      *(float4*)&Bs[r][c] = *(const float4*)&W_lin[(size_t)(k0 + r) * HH + j0 + c]; }
    __syncthreads();
    #pragma unroll
    for (int k = 0; k < 16; ++k) {
      float a[4], bv[4];
      #pragma unroll
      for (int i = 0; i < 4; ++i) a[i] = As[tn*4+i][k];
      #pragma unroll
      for (int m = 0; m < 4; ++m) bv[m] = Bs[k][tj*4+m];
      #pragma unroll
      for (int i = 0; i < 4; ++i)
        #pragma unroll
        for (int m = 0; m < 4; ++m)
          acc[i][m] = fmaf(a[i], bv[m], acc[i][m]);
    }
    __syncthreads();
  }
  #pragma unroll
  for (int i = 0; i < 4; ++i) {
    int n = n0 + tn*4 + i;
    #pragma unroll
    for (int m = 0; m < 4; ++m) {
      int j = j0 + tj*4 + m;
      Wbig16[(size_t)n*HH + j] = (f16)(acc[i][m] + W_hh[(size_t)n*HH + j]);
    }
  }
}

// bias0[n] = b_ih+b_hh ; bias1[n] = bias0[n] + dot(W_ih[n,:], b_lin)
__global__ void prep_bias(const float* __restrict__ b_ih, const float* __restrict__ b_hh,
                          const float* __restrict__ W_ih, const float* __restrict__ b_lin,
                          float* __restrict__ bias0, float* __restrict__ bias1)
{
  int n = blockIdx.x * 256 + threadIdx.x;   // grid 8
  float s = b_ih[n] + b_hh[n];
  float d = 0.f;
  for (int k = 0; k < DD; ++k) d = fmaf(W_ih[(size_t)n*DD + k], b_lin[k], d);
  bias0[n] = s;
  bias1[n] = s + d;
}

// fp32 -> fp16 conversion of W_ih | W_hh | W_lin (concatenated flat index)
#define NIH (G4H*DD)            // 524288
#define NHH (G4H*HH)            // 1048576
#define NLIN (DD*HH)            // 131072
__global__ void prep_cvtw(const float* __restrict__ W_ih, const float* __restrict__ W_hh,
                          const float* __restrict__ W_lin,
                          f16* __restrict__ Wih16, f16* __restrict__ Whh16,
                          f16* __restrict__ Wlin16)
{
  int e = blockIdx.x * 256 + threadIdx.x;   // grid 6656 -> 1703936
  if (e < NIH) Wih16[e] = (f16)W_ih[e];
  else if (e < NIH + NHH) Whh16[e - NIH] = (f16)W_hh[e - NIH];
  else Wlin16[e - NIH - NHH] = (f16)W_lin[e - NIH - NHH];
}

// init: bh/bc from h0/c0, cbuf=c0, x0/h0 hi-lo fp16 splits, barrier vars
__global__ void prep_init(const float* __restrict__ x0, const float* __restrict__ h0,
                          const float* __restrict__ c0,
                          float* __restrict__ bh, float* __restrict__ bc,
                          float* __restrict__ cbuf,
                          f16* __restrict__ x0hi, f16* __restrict__ x0lo,
                          f16* __restrict__ h0hi, f16* __restrict__ h0lo,
                          int* __restrict__ bars)
{
  int e = blockIdx.x * 256 + threadIdx.x;   // grid 4096 -> 1048576
  int r = e & (BH - 1);
  bh[e] = h0[r];
  bc[e] = c0[r];
  if (e < BH) {
    cbuf[e] = c0[e];
    float v = h0[e];
    f16 hi = (f16)v;
    h0hi[e] = hi;
    h0lo[e] = (f16)(v - (float)hi);
  }
  if (e < BB*DD) {
    int b = e >> 8, d = e & 255;
    float v = x0[(size_t)b*(TT*DD) + d];
    f16 hi = (f16)v;
    x0hi[e] = hi;
    x0lo[e] = (f16)(v - (float)hi);
  }
  if (e < 128) bars[e] = 0;
}

// ---------------- persistent main kernel ----------------

__device__ __forceinline__ void group_barrier(int* cnt, int* phs) {
  __threadfence();
  __syncthreads();
  if (threadIdx.x == 0) {
    int ph = __hip_atomic_load(phs, __ATOMIC_RELAXED, __HIP_MEMORY_SCOPE_AGENT);
    if (__hip_atomic_fetch_add(cnt, 1, __ATOMIC_ACQ_REL, __HIP_MEMORY_SCOPE_AGENT)
        == BLK_PER_GRP - 1) {
      __hip_atomic_store(cnt, 0, __ATOMIC_RELAXED, __HIP_MEMORY_SCOPE_AGENT);
      __hip_atomic_store(phs, ph + 1, __ATOMIC_RELEASE, __HIP_MEMORY_SCOPE_AGENT);
    } else {
      while (__hip_atomic_load(phs, __ATOMIC_ACQUIRE, __HIP_MEMORY_SCOPE_AGENT) == ph)
        __builtin_amdgcn_s_sleep(1);
    }
  }
  __syncthreads();
}

// stage 32 rows x 512 cols of hi/lo fp16 into XOR-swizzled LDS
__device__ __forceinline__ void stageA(const f16* __restrict__ shi,
                                       const f16* __restrict__ slo,
                                       int b0, f16* Ahi, f16* Alo, int tid) {
  #pragma unroll
  for (int i = 0; i < 8; ++i) {
    int lin = i * 256 + tid;          // 2048 chunks of 16B (32 rows x 64)
    int r = lin >> 6, c16 = lin & 63;
    uint4 vh = *(const uint4*)(shi + (size_t)(b0 + r) * HH + c16 * 8);
    uint4 vl = *(const uint4*)(slo + (size_t)(b0 + r) * HH + c16 * 8);
    int off = r * 1024 + ((c16 * 16) ^ (r << 4));
    *(uint4*)((char*)Ahi + off) = vh;
    *(uint4*)((char*)Alo + off) = vl;
  }
}

// K=512 2-pass (hi+lo) MFMA GEMM from swizzled LDS, W frags in registers
__device__ __forceinline__ f32x16 gemmA(const f16x8 (&wreg)[32],
                                        const f16* Ahi, const f16* Alo,
                                        int rbase, int kselB, int key) {
  f32x16 acc;
  #pragma unroll
  for (int i = 0; i < 16; ++i) acc[i] = 0.f;
  #pragma unroll
  for (int ks = 0; ks < 32; ++ks) {
    int off = rbase + (((ks << 5) + kselB) ^ key);
    f16x8 ah = *(const f16x8*)((const char*)Ahi + off);
    f16x8 al = *(const f16x8*)((const char*)Alo + off);
    acc = __builtin_amdgcn_mfma_f32_32x32x16_f16(ah, wreg[ks], acc, 0, 0, 0);
    acc = __builtin_amdgcn_mfma_f32_32x32x16_f16(al, wreg[ks], acc, 0, 0, 0);
  }
  return acc;
}

__global__ __launch_bounds__(256) void lstm_persist(
    const f16* __restrict__ x0hi, const f16* __restrict__ x0lo,
    const f16* __restrict__ h0hi, const f16* __restrict__ h0lo,
    const f16* __restrict__ Wih16, const f16* __restrict__ Whh16,
    const f16* __restrict__ Wbig16, const f16* __restrict__ Wlin16,
    const float* __restrict__ bias0, const float* __restrict__ bias1,
    const float* __restrict__ b_lin,
    const int* __restrict__ w1, const int* __restrict__ w2,
    f16* __restrict__ hbufH, f16* __restrict__ hbufL,   // 2 slots each
    float* __restrict__ cbuf,
    float* __restrict__ bh, float* __restrict__ bc,
    int* __restrict__ bars,
    float* __restrict__ outp)
{
  __shared__ f16 AhiS[GRP_ROWS * HH];   // 32 KB, XOR-swizzled
  __shared__ f16 AloS[GRP_ROWS * HH];   // 32 KB
  __shared__ float gbuf[4 * 1024];      // 16 KB: per-gate 32x32 tiles

  const int tid  = threadIdx.x;
  const int lane = tid & 63;
  const int wv   = tid >> 6;            // wave 0..3
  const int bid  = blockIdx.x;
  const int grp  = bid & 7;
  const int role = bid >> 3;            // 0..15 gates (jt), 16..17 out
  const bool isG = role < 16;
  const int b0   = grp * GRP_ROWS;

  const int row   = lane & 31;
  const int ksel8 = (lane >> 5) * 8;    // element offset of k-group
  const int kselB = ksel8 * 2;          // bytes
  const int rbase = row * 1024;
  const int key   = row << 4;

  int* cnt = bars + grp * 16;
  int* phs = bars + grp * 16 + 8;

  // ---- persistent W fragments (K=512 -> 32 frags = 128 VGPR) ----
  f16x8 wreg[32];
  int wrow;         // W row this lane owns (gates: n index; out: d index)
  const f16* wbase;
  if (isG) {
    wrow  = (wv << 9) + (role << 5) + row;        // gate*512 + jt*32 + row
    wbase = Wbig16 + (size_t)wrow * HH;
  } else {
    wrow  = (((role - 16) << 2) + wv) * 32 + row; // d-tile*32 + row
    wbase = Wlin16 + (size_t)wrow * HH;
  }
  #pragma unroll
  for (int ks = 0; ks < 32; ++ks)
    wreg[ks] = *(const f16x8*)(wbase + ks * 16 + ksel8);

  float bld = 0.f;
  int dcol = 0;
  if (!isG) { dcol = wrow; bld = b_lin[dcol]; }   // lane's out column + bias

  const int jt = role;          // gates j-tile

  // ================= t = 0 (gates blocks only) =================
  if (isG) {
    f32x16 acc;
    #pragma unroll
    for (int i = 0; i < 16; ++i) acc[i] = 0.f;
    const f16* arh = x0hi + (size_t)(b0 + row) * DD;
    const f16* arl = x0lo + (size_t)(b0 + row) * DD;
    const f16* wr1 = Wih16 + (size_t)wrow * DD;
    #pragma unroll
    for (int ks = 0; ks < 16; ++ks) {          // K=256 over x0 / W_ih
      int ko = ks * 16 + ksel8;
      f16x8 w = *(const f16x8*)(wr1 + ko);
      acc = __builtin_amdgcn_mfma_f32_32x32x16_f16(*(const f16x8*)(arh + ko), w, acc, 0,0,0);
      acc = __builtin_amdgcn_mfma_f32_32x32x16_f16(*(const f16x8*)(arl + ko), w, acc, 0,0,0);
    }
    const f16* brh = h0hi + (size_t)(b0 + row) * HH;
    const f16* brl = h0lo + (size_t)(b0 + row) * HH;
    const f16* wr2 = Whh16 + (size_t)wrow * HH;
    #pragma unroll
    for (int ks = 0; ks < 32; ++ks) {          // K=512 over h0 / W_hh
      int ko = ks * 16 + ksel8;
      f16x8 w = *(const f16x8*)(wr2 + ko);
      acc = __builtin_amdgcn_mfma_f32_32x32x16_f16(*(const f16x8*)(brh + ko), w, acc, 0,0,0);
      acc = __builtin_amdgcn_mfma_f32_32x32x16_f16(*(const f16x8*)(brl + ko), w, acc, 0,0,0);
    }
    // ---- epilogue t=0 ----
    {
      const int col = lane & 31, rh = (lane >> 5) * 4;
      #pragma unroll
      for (int rg = 0; rg < 16; ++rg) {
        int m = (rg & 3) + ((rg >> 2) << 3) + rh;
        gbuf[(wv << 10) + (m << 5) + col] = acc[rg];
      }
      __syncthreads();
      const float a1 = (float)w1[0], a2 = (float)w2[0];
      const float nrm = 1.f / (a1 + a2);
      #pragma unroll
      for (int i = 0; i < 4; ++i) {
        int c = (i << 8) + tid;
        int bl = c >> 5, jl = c & 31;
        int j = (jt << 5) + jl;
        size_t idx = (size_t)(b0 + bl) * HH + j;
        float pi = gbuf[c]          + bias0[j];
        float pf = gbuf[1024 + c]   + bias0[HH + j];
        float pg = gbuf[2048 + c]   + bias0[2*HH + j];
        float po = gbuf[3072 + c]   + bias0[3*HH + j];
        float i_ = sigm(pi), f_ = sigm(pf), o_ = sigm(po), g_ = ftanh(pg);
        float cold = cbuf[idx];
        float cnew = fmaf(f_, cold, i_ * g_);
        float hnew = o_ * ftanh(cnew);
        size_t bx = idx;                         // pos = 0
        float sh = bh[bx], sc = bc[bx];
        bh[bx] = hnew; bc[bx] = cnew;
        float ch = (a1 * hnew + a2 * ftanh(sh)) * nrm;
        float cc = (a1 * cnew + a2 * ftanh(sc)) * nrm;
        cbuf[idx] = cc;
        f16 chh = (f16)ch;
        hbufH[idx] = chh;                        // slot 0
        hbufL[idx] = (f16)(ch - (float)chh);
      }
    }
  }

  // ================= main loop t = 1..512 =================
  for (int t = 1; t <= TT; ++t) {
    group_barrier(cnt, phs);
    const int slotR = (t - 1) & 1;
    const f16* shi = hbufH + (size_t)slotR * BH;
    const f16* slo = hbufL + (size_t)slotR * BH;

    if (isG) {
      if (t < TT) {
        stageA(shi, slo, b0, AhiS, AloS, tid);
        __syncthreads();
        f32x16 acc = gemmA(wreg, AhiS, AloS, rbase, kselB, key);
        // ---- epilogue ----
        const int col = lane & 31, rh = (lane >> 5) * 4;
        #pragma unroll
        for (int rg = 0; rg < 16; ++rg) {
          int m = (rg & 3) + ((rg >> 2) << 3) + rh;
          gbuf[(wv << 10) + (m << 5) + col] = acc[rg];
        }
        __syncthreads();
        const float a1 = (float)w1[t], a2 = (float)w2[t];
        const float nrm = 1.f / (a1 + a2);
        const int pos = t & (SS - 1);
        const int slotW = t & 1;
        #pragma unroll
        for (int i = 0; i < 4; ++i) {
          int c = (i << 8) + tid;
          int bl = c >> 5, jl = c & 31;
          int j = (jt << 5) + jl;
          size_t idx = (size_t)(b0 + bl) * HH + j;
          float pi = gbuf[c]          + bias1[j];
          float pf = gbuf[1024 + c]   + bias1[HH + j];
          float pg = gbuf[2048 + c]   + bias1[2*HH + j];
          float po = gbuf[3072 + c]   + bias1[3*HH + j];
          float i_ = sigm(pi), f_ = sigm(pf), o_ = sigm(po), g_ = ftanh(pg);
          float cold = cbuf[idx];
          float cnew = fmaf(f_, cold, i_ * g_);
          float hnew = o_ * ftanh(cnew);
          size_t bx = (size_t)pos * BH + idx;
          float sh = bh[bx], sc = bc[bx];
          bh[bx] = hnew; bc[bx] = cnew;
          float ch = (a1 * hnew + a2 * ftanh(sh)) * nrm;
          float cc = (a1 * cnew + a2 * ftanh(sc)) * nrm;
          cbuf[idx] = cc;
          f16 chh = (f16)ch;
          hbufH[(size_t)slotW * BH + idx] = chh;
          hbufL[(size_t)slotW * BH + idx] = (f16)(ch - (float)chh);
          if (t == TT - 1) {
            outp[OUT_BASE + idx] = ch;           // h_fin
            outp[OUT_BASE + BH + idx] = cc;      // c_fin
          }
        }
      }
    } else {
      // out blocks: out[t-1] = comb_h[t-1] @ W_lin^T + b_lin
      stageA(shi, slo, b0, AhiS, AloS, tid);
      __syncthreads();
      f32x16 acc = gemmA(wreg, AhiS, AloS, rbase, kselB, key);
      const int tcol = (t - 1) * DD + dcol;
      #pragma unroll
      for (int rg = 0; rg < 16; ++rg) {
        int m = (rg & 3) + ((rg >> 2) << 3) + ((lane >> 5) << 2);
        outp[(size_t)(b0 + m) * (TT*DD) + tcol] = acc[rg] + bld;
      }
      __syncthreads();   // keep block together before next stage overwrites LDS
    }
  }
}

// ---------------- host launch ----------------

extern "C" void kernel_launch(void* const* d_in, const int* in_sizes, int n_in,
                              void* d_out, int out_size, void* d_ws, size_t ws_size,
                              hipStream_t stream)
{
  const float* x0    = (const float*)d_in[0];
  const float* h0    = (const float*)d_in[1];
  const float* c0    = (const float*)d_in[2];
  const float* W_ih  = (const float*)d_in[3];
  const float* W_hh  = (const float*)d_in[4];
  const float* b_ih  = (const float*)d_in[5];
  const float* b_hh  = (const float*)d_in[6];
  const float* W_lin = (const float*)d_in[7];
  const float* b_lin = (const float*)d_in[8];
  const int*   w1    = (const int*)d_in[9];
  const int*   w2    = (const int*)d_in[10];

  char* p = (char*)d_ws;
  f16* Wbig16 = (f16*)p;            p += (size_t)G4H*HH*2;
  f16* Wih16  = (f16*)p;            p += (size_t)G4H*DD*2;
  f16* Whh16  = (f16*)p;            p += (size_t)G4H*HH*2;
  f16* Wlin16 = (f16*)p;            p += (size_t)DD*HH*2;
  f16* x0hi   = (f16*)p;            p += (size_t)BB*DD*2;
  f16* x0lo   = (f16*)p;            p += (size_t)BB*DD*2;
  f16* h0hi   = (f16*)p;            p += (size_t)BH*2;
  f16* h0lo   = (f16*)p;            p += (size_t)BH*2;
  f16* hbufH  = (f16*)p;            p += (size_t)2*BH*2;
  f16* hbufL  = (f16*)p;            p += (size_t)2*BH*2;
  float* cbuf = (float*)p;          p += (size_t)BH*4;
  float* bh   = (float*)p;          p += (size_t)SS*BH*4;
  float* bc   = (float*)p;          p += (size_t)SS*BH*4;
  float* bias0= (float*)p;          p += G4H*4;
  float* bias1= (float*)p;          p += G4H*4;
  int*  bars  = (int*)p;            p += 128*4;
  float* outp = (float*)d_out;

  hipLaunchKernelGGL(prep_wbig16, dim3(32, 8), dim3(256), 0, stream,
                     W_ih, W_hh, W_lin, Wbig16);
  hipLaunchKernelGGL(prep_bias, dim3(8), dim3(256), 0, stream,
                     b_ih, b_hh, W_ih, b_lin, bias0, bias1);
  hipLaunchKernelGGL(prep_cvtw, dim3(6656), dim3(256), 0, stream,
                     W_ih, W_hh, W_lin, Wih16, Whh16, Wlin16);
  hipLaunchKernelGGL(prep_init, dim3(4096), dim3(256), 0, stream,
                     x0, h0, c0, bh, bc, cbuf, x0hi, x0lo, h0hi, h0lo, bars);

  hipLaunchKernelGGL(lstm_persist, dim3(NGRP * BLK_PER_GRP), dim3(256), 0, stream,
                     x0hi, x0lo, h0hi, h0lo, Wih16, Whh16, Wbig16, Wlin16,
                     bias0, bias1, b_lin, w1, w2,
                     hbufH, hbufL, cbuf, bh, bc, bars, outp);
}

// Round 5
// 4595.249 us; speedup vs baseline: 3.2326x; 2.7612x over previous
//
#include <hip/hip_runtime.h>
#include <math.h>

#define BB 256
#define TT 512
#define DD 256
#define HH 512
#define SS 8
#define G4H 2048
#define BH (BB*HH)          // 131072
#define OUT_BASE ((size_t)BB*TT*DD)
#define NARR 9              // blocks per group arriving at barrier

typedef _Float16 f16;
typedef __attribute__((ext_vector_type(8)))  _Float16 f16x8;
typedef __attribute__((ext_vector_type(16))) float    f32x16;

__device__ __forceinline__ float sigm(float x) { return 1.f / (1.f + __expf(-x)); }
__device__ __forceinline__ float ftanh(float x) {
  x = fminf(15.f, fmaxf(-15.f, x));
  float e = __expf(-2.f * x);
  return (1.f - e) / (1.f + e);
}

// ---------------- prep kernels ----------------

// W_big[n][j] = sum_d W_ih[n][d]*W_lin[d][j] + W_hh[n][j]  -> fp16 (2048x512)
__global__ __launch_bounds__(256) void prep_wbig16(
    const float* __restrict__ W_ih, const float* __restrict__ W_hh,
    const float* __restrict__ W_lin, f16* __restrict__ Wbig16)
{
  __shared__ float As[64][20];
  __shared__ float Bs[16][68];
  const int n0 = blockIdx.x * 64;
  const int j0 = blockIdx.y * 64;
  const int tid = threadIdx.x;
  const int tn = tid >> 4, tj = tid & 15;
  float acc[4][4] = {};
  for (int k0 = 0; k0 < DD; k0 += 16) {
    { int r = tid >> 2, c = (tid & 3) * 4;
      *(float4*)&As[r][c] = *(const float4*)&W_ih[(size_t)(n0 + r) * DD + k0 + c]; }
    { int r = tid >> 4, c = (tid & 15) * 4;
      *(float4*)&Bs[r][c] = *(const float4*)&W_lin[(size_t)(k0 + r) * HH + j0 + c]; }
    __syncthreads();
    #pragma unroll
    for (int k = 0; k < 16; ++k) {
      float a[4], bv[4];
      #pragma unroll
      for (int i = 0; i < 4; ++i) a[i] = As[tn*4+i][k];
      #pragma unroll
      for (int m = 0; m < 4; ++m) bv[m] = Bs[k][tj*4+m];
      #pragma unroll
      for (int i = 0; i < 4; ++i)
        #pragma unroll
        for (int m = 0; m < 4; ++m)
          acc[i][m] = fmaf(a[i], bv[m], acc[i][m]);
    }
    __syncthreads();
  }
  #pragma unroll
  for (int i = 0; i < 4; ++i) {
    int n = n0 + tn*4 + i;
    #pragma unroll
    for (int m = 0; m < 4; ++m) {
      int j = j0 + tj*4 + m;
      Wbig16[(size_t)n*HH + j] = (f16)(acc[i][m] + W_hh[(size_t)n*HH + j]);
    }
  }
}

// bias0[n] = b_ih+b_hh ; bias1[n] = bias0[n] + dot(W_ih[n,:], b_lin)
__global__ void prep_bias(const float* __restrict__ b_ih, const float* __restrict__ b_hh,
                          const float* __restrict__ W_ih, const float* __restrict__ b_lin,
                          float* __restrict__ bias0, float* __restrict__ bias1)
{
  int n = blockIdx.x * 256 + threadIdx.x;   // grid 8
  float s = b_ih[n] + b_hh[n];
  float d = 0.f;
  for (int k = 0; k < DD; ++k) d = fmaf(W_ih[(size_t)n*DD + k], b_lin[k], d);
  bias0[n] = s;
  bias1[n] = s + d;
}

// fp32 -> fp16 conversion of W_ih | W_hh | W_lin
#define NIH (G4H*DD)
#define NHH (G4H*HH)
__global__ void prep_cvtw(const float* __restrict__ W_ih, const float* __restrict__ W_hh,
                          const float* __restrict__ W_lin,
                          f16* __restrict__ Wih16, f16* __restrict__ Whh16,
                          f16* __restrict__ Wlin16)
{
  int e = blockIdx.x * 256 + threadIdx.x;   // grid 6656
  if (e < NIH) Wih16[e] = (f16)W_ih[e];
  else if (e < NIH + NHH) Whh16[e - NIH] = (f16)W_hh[e - NIH];
  else Wlin16[e - NIH - NHH] = (f16)W_lin[e - NIH - NHH];
}

// init: bh/bc from h0/c0, x0/h0 hi-lo fp16 splits, step constants, barrier vars
__global__ void prep_init(const float* __restrict__ x0, const float* __restrict__ h0,
                          const float* __restrict__ c0,
                          const int* __restrict__ w1, const int* __restrict__ w2,
                          float* __restrict__ bh, float* __restrict__ bc,
                          f16* __restrict__ x0hi, f16* __restrict__ x0lo,
                          f16* __restrict__ h0hi, f16* __restrict__ h0lo,
                          float4* __restrict__ stepc,
                          int* __restrict__ bars)
{
  int e = blockIdx.x * 256 + threadIdx.x;   // grid 4096 -> 1048576
  int r = e & (BH - 1);
  bh[e] = h0[r];
  bc[e] = c0[r];
  if (e < BH) {
    float v = h0[e];
    f16 hi = (f16)v;
    h0hi[e] = hi;
    h0lo[e] = (f16)(v - (float)hi);
  }
  if (e < BB*DD) {
    int b = e >> 8, d = e & 255;
    float v = x0[(size_t)b*(TT*DD) + d];
    f16 hi = (f16)v;
    x0hi[e] = hi;
    x0lo[e] = (f16)(v - (float)hi);
  }
  if (e < TT) {
    float a1 = (float)w1[e], a2 = (float)w2[e];
    stepc[e] = make_float4(a1, a2, 1.f / (a1 + a2), 0.f);
  }
  if (e < 128) bars[e] = 0;
}

// ---------------- persistent main kernel ----------------

// thread-0-only barrier: one release fence + one acquire fence per block per step.
__device__ __forceinline__ void group_barrier(int* cnt, int* phs) {
  __syncthreads();
  if (threadIdx.x == 0) {
    __builtin_amdgcn_fence(__ATOMIC_RELEASE, "agent");
    int ph = __hip_atomic_load(phs, __ATOMIC_RELAXED, __HIP_MEMORY_SCOPE_AGENT);
    if (__hip_atomic_fetch_add(cnt, 1, __ATOMIC_RELAXED, __HIP_MEMORY_SCOPE_AGENT)
        == NARR - 1) {
      __hip_atomic_store(cnt, 0, __ATOMIC_RELAXED, __HIP_MEMORY_SCOPE_AGENT);
      __hip_atomic_store(phs, ph + 1, __ATOMIC_RELEASE, __HIP_MEMORY_SCOPE_AGENT);
    } else {
      while (__hip_atomic_load(phs, __ATOMIC_RELAXED, __HIP_MEMORY_SCOPE_AGENT) == ph)
        __builtin_amdgcn_s_sleep(2);
    }
    __builtin_amdgcn_fence(__ATOMIC_ACQUIRE, "agent");
  }
  __syncthreads();
}

// stage 32 rows x 512 cols hi/lo fp16 into XOR-swizzled LDS (512 threads)
__device__ __forceinline__ void stageA(const f16* __restrict__ shi,
                                       const f16* __restrict__ slo,
                                       int b0, f16* Ahi, f16* Alo, int tid) {
  #pragma unroll
  for (int i = 0; i < 4; ++i) {
    int lin = i * 512 + tid;          // 2048 chunks of 16B
    int r = lin >> 6, c16 = lin & 63;
    uint4 vh = *(const uint4*)(shi + (size_t)(b0 + r) * HH + c16 * 8);
    uint4 vl = *(const uint4*)(slo + (size_t)(b0 + r) * HH + c16 * 8);
    int off = r * 1024 + ((c16 * 16) ^ (r << 4));
    *(uint4*)((char*)Ahi + off) = vh;
    *(uint4*)((char*)Alo + off) = vl;
  }
}

// K=512 2-pass (hi+lo) MFMA GEMM from swizzled LDS, W frags in registers
__device__ __forceinline__ f32x16 gemmA(const f16x8 (&wreg)[32],
                                        const f16* Ahi, const f16* Alo,
                                        int rbase, int kselB, int key) {
  f32x16 acc;
  #pragma unroll
  for (int i = 0; i < 16; ++i) acc[i] = 0.f;
  #pragma unroll
  for (int ks = 0; ks < 32; ++ks) {
    int off = rbase + (((ks << 5) + kselB) ^ key);
    f16x8 ah = *(const f16x8*)((const char*)Ahi + off);
    f16x8 al = *(const f16x8*)((const char*)Alo + off);
    acc = __builtin_amdgcn_mfma_f32_32x32x16_f16(ah, wreg[ks], acc, 0, 0, 0);
    acc = __builtin_amdgcn_mfma_f32_32x32x16_f16(al, wreg[ks], acc, 0, 0, 0);
  }
  return acc;
}

// 72 blocks x 512 threads. Group g = blockIdx&7 owns batch rows [32g, 32g+32).
// role = blockIdx>>3: 0..7 gates (64 j-cols x 4 gates each), 8 = out projection.
__global__ __launch_bounds__(512, 2) void lstm_persist(
    const f16* __restrict__ x0hi, const f16* __restrict__ x0lo,
    const f16* __restrict__ h0hi, const f16* __restrict__ h0lo,
    const float* __restrict__ c0,
    const f16* __restrict__ Wih16, const f16* __restrict__ Whh16,
    const f16* __restrict__ Wbig16, const f16* __restrict__ Wlin16,
    const float* __restrict__ bias0, const float* __restrict__ bias1,
    const float* __restrict__ b_lin,
    const float4* __restrict__ stepc,
    f16* __restrict__ hbufH, f16* __restrict__ hbufL,   // 2 slots each
    float* __restrict__ bh, float* __restrict__ bc,     // SS x B*H skip bufs
    int* __restrict__ bars,
    float* __restrict__ outp)
{
  __shared__ f16 AhiS[32 * HH];     // 32 KB, XOR-swizzled
  __shared__ f16 AloS[32 * HH];     // 32 KB
  __shared__ float gbuf[4 * 2048];  // 32 KB: [gate][32 b][64 j]

  const int tid  = threadIdx.x;
  const int lane = tid & 63;
  const int wv   = tid >> 6;            // wave 0..7
  const int grp  = blockIdx.x & 7;
  const int role = blockIdx.x >> 3;     // 0..8
  const bool isG = role < 8;
  const int b0   = grp * 32;

  const int row   = lane & 31;
  const int ksel8 = (lane >> 5) * 8;
  const int kselB = ksel8 * 2;
  const int rbase = row * 1024;
  const int key   = row << 4;

  int* cnt = bars + grp * 16;
  int* phs = cnt + 8;

  // ---- persistent W fragments (K=512 -> 32 frags = 128 VGPR) ----
  int wrow;
  const f16* wbase;
  if (isG) {
    // gate = wv&3, j-window = role*64 + (wv>>2)*32
    wrow  = (wv & 3) * 512 + role * 64 + (wv >> 2) * 32 + row;
    wbase = Wbig16 + (size_t)wrow * HH;
  } else {
    wrow  = wv * 32 + row;              // d-column
    wbase = Wlin16 + (size_t)wrow * HH;
  }
  f16x8 wreg[32];
  #pragma unroll
  for (int ks = 0; ks < 32; ++ks)
    wreg[ks] = *(const f16x8*)(wbase + ks * 16 + ksel8);

  const float bld = isG ? 0.f : b_lin[wrow];

  // ---- gates per-thread epilogue constants (registers) ----
  int   eidx[4], jv[4];
  float bI[4], bF[4], bG[4], bO[4], creg[4];
  if (isG) {
    #pragma unroll
    for (int i = 0; i < 4; ++i) {
      int c = i * 512 + tid;
      int bl = c >> 6, jl = c & 63;
      int j = role * 64 + jl;
      jv[i]   = j;
      eidx[i] = (b0 + bl) * HH + j;
      bI[i] = bias1[j];          bF[i] = bias1[512 + j];
      bG[i] = bias1[1024 + j];   bO[i] = bias1[1536 + j];
      creg[i] = c0[eidx[i]];
    }
  }

  for (int t = 0; t <= TT; ++t) {
    if (t > 0) group_barrier(cnt, phs);

    if (isG) {
      if (t < TT) {
        // prefetch step constants + skip-buffer reads (hidden under GEMM)
        const float4 sc = stepc[t];
        const int pos = t & (SS - 1);
        float shv[4], scv[4];
        #pragma unroll
        for (int i = 0; i < 4; ++i) {
          int bx = pos * BH + eidx[i];
          shv[i] = bh[bx];
          scv[i] = bc[bx];
        }

        f32x16 acc;
        if (t == 0) {
          #pragma unroll
          for (int i = 0; i < 16; ++i) acc[i] = 0.f;
          const f16* arh = x0hi + (size_t)(b0 + row) * DD;
          const f16* arl = x0lo + (size_t)(b0 + row) * DD;
          const f16* w1p = Wih16 + (size_t)wrow * DD;
          #pragma unroll
          for (int ks = 0; ks < 16; ++ks) {       // K=256: x0 @ W_ih^T
            int ko = ks * 16 + ksel8;
            f16x8 w = *(const f16x8*)(w1p + ko);
            acc = __builtin_amdgcn_mfma_f32_32x32x16_f16(*(const f16x8*)(arh + ko), w, acc, 0,0,0);
            acc = __builtin_amdgcn_mfma_f32_32x32x16_f16(*(const f16x8*)(arl + ko), w, acc, 0,0,0);
          }
          const f16* brh = h0hi + (size_t)(b0 + row) * HH;
          const f16* brl = h0lo + (size_t)(b0 + row) * HH;
          const f16* w2p = Whh16 + (size_t)wrow * HH;
          #pragma unroll
          for (int ks = 0; ks < 32; ++ks) {       // K=512: h0 @ W_hh^T
            int ko = ks * 16 + ksel8;
            f16x8 w = *(const f16x8*)(w2p + ko);
            acc = __builtin_amdgcn_mfma_f32_32x32x16_f16(*(const f16x8*)(brh + ko), w, acc, 0,0,0);
            acc = __builtin_amdgcn_mfma_f32_32x32x16_f16(*(const f16x8*)(brl + ko), w, acc, 0,0,0);
          }
        } else {
          const int slotR = (t - 1) & 1;
          stageA(hbufH + (size_t)slotR * BH, hbufL + (size_t)slotR * BH, b0, AhiS, AloS, tid);
          __syncthreads();
          acc = gemmA(wreg, AhiS, AloS, rbase, kselB, key);
        }

        // reshuffle acc -> gbuf [gate][b][j]
        {
          const int col = lane & 31;
          const int g4 = wv & 3, jh = wv >> 2;
          #pragma unroll
          for (int rg = 0; rg < 16; ++rg) {
            int m = (rg & 3) + ((rg >> 2) << 3) + ((lane >> 5) << 2);
            gbuf[g4 * 2048 + m * 64 + jh * 32 + col] = acc[rg];
          }
        }
        __syncthreads();

        // fused elementwise LSTM + skip combine
        const float a1 = sc.x, a2 = sc.y, nrm = sc.z;
        const int slotW = t & 1;
        #pragma unroll
        for (int i = 0; i < 4; ++i) {
          int c = i * 512 + tid;
          float baI = bI[i], baF = bF[i], baG = bG[i], baO = bO[i];
          if (t == 0) {
            baI = bias0[jv[i]];        baF = bias0[512 + jv[i]];
            baG = bias0[1024 + jv[i]]; baO = bias0[1536 + jv[i]];
          }
          float pi = gbuf[c]        + baI;
          float pf = gbuf[2048 + c] + baF;
          float pg = gbuf[4096 + c] + baG;
          float po = gbuf[6144 + c] + baO;
          float i_ = sigm(pi), f_ = sigm(pf), o_ = sigm(po), g_ = ftanh(pg);
          float cnew = fmaf(f_, creg[i], i_ * g_);
          float hnew = o_ * ftanh(cnew);
          float ch = (a1 * hnew + a2 * ftanh(shv[i])) * nrm;
          float cc = (a1 * cnew + a2 * ftanh(scv[i])) * nrm;
          creg[i] = cc;
          int bx = pos * BH + eidx[i];
          __builtin_nontemporal_store(hnew, &bh[bx]);
          __builtin_nontemporal_store(cnew, &bc[bx]);
          f16 chh = (f16)ch;
          f16 chl = (f16)(ch - (float)chh);
          __builtin_nontemporal_store(chh, &hbufH[(size_t)slotW * BH + eidx[i]]);
          __builtin_nontemporal_store(chl, &hbufL[(size_t)slotW * BH + eidx[i]]);
          if (t == TT - 1) {
            __builtin_nontemporal_store(ch, &outp[OUT_BASE + eidx[i]]);        // h_fin
            __builtin_nontemporal_store(cc, &outp[OUT_BASE + BH + eidx[i]]);   // c_fin
          }
        }
      }
    } else {
      if (t >= 1) {
        // out[t-1] = comb_h[t-1] @ W_lin^T + b_lin
        const int slotR = (t - 1) & 1;
        stageA(hbufH + (size_t)slotR * BH, hbufL + (size_t)slotR * BH, b0, AhiS, AloS, tid);
        __syncthreads();
        f32x16 acc = gemmA(wreg, AhiS, AloS, rbase, kselB, key);
        const size_t tbase = (size_t)(t - 1) * DD + wrow;
        #pragma unroll
        for (int rg = 0; rg < 16; ++rg) {
          int m = (rg & 3) + ((rg >> 2) << 3) + ((lane >> 5) << 2);
          __builtin_nontemporal_store(acc[rg] + bld,
                                      &outp[(size_t)(b0 + m) * (TT*DD) + tbase]);
        }
      }
    }
  }
}

// ---------------- host launch ----------------

extern "C" void kernel_launch(void* const* d_in, const int* in_sizes, int n_in,
                              void* d_out, int out_size, void* d_ws, size_t ws_size,
                              hipStream_t stream)
{
  const float* x0    = (const float*)d_in[0];
  const float* h0    = (const float*)d_in[1];
  const float* c0    = (const float*)d_in[2];
  const float* W_ih  = (const float*)d_in[3];
  const float* W_hh  = (const float*)d_in[4];
  const float* b_ih  = (const float*)d_in[5];
  const float* b_hh  = (const float*)d_in[6];
  const float* W_lin = (const float*)d_in[7];
  const float* b_lin = (const float*)d_in[8];
  const int*   w1    = (const int*)d_in[9];
  const int*   w2    = (const int*)d_in[10];

  char* p = (char*)d_ws;
  f16* Wbig16 = (f16*)p;            p += (size_t)G4H*HH*2;
  f16* Wih16  = (f16*)p;            p += (size_t)G4H*DD*2;
  f16* Whh16  = (f16*)p;            p += (size_t)G4H*HH*2;
  f16* Wlin16 = (f16*)p;            p += (size_t)DD*HH*2;
  f16* x0hi   = (f16*)p;            p += (size_t)BB*DD*2;
  f16* x0lo   = (f16*)p;            p += (size_t)BB*DD*2;
  f16* h0hi   = (f16*)p;            p += (size_t)BH*2;
  f16* h0lo   = (f16*)p;            p += (size_t)BH*2;
  f16* hbufH  = (f16*)p;            p += (size_t)2*BH*2;
  f16* hbufL  = (f16*)p;            p += (size_t)2*BH*2;
  float* bh   = (float*)p;          p += (size_t)SS*BH*4;
  float* bc   = (float*)p;          p += (size_t)SS*BH*4;
  float* bias0= (float*)p;          p += G4H*4;
  float* bias1= (float*)p;          p += G4H*4;
  float4* stepc = (float4*)p;       p += (size_t)TT*16;
  int*  bars  = (int*)p;            p += 128*4;
  float* outp = (float*)d_out;

  hipLaunchKernelGGL(prep_wbig16, dim3(32, 8), dim3(256), 0, stream,
                     W_ih, W_hh, W_lin, Wbig16);
  hipLaunchKernelGGL(prep_bias, dim3(8), dim3(256), 0, stream,
                     b_ih, b_hh, W_ih, b_lin, bias0, bias1);
  hipLaunchKernelGGL(prep_cvtw, dim3(6656), dim3(256), 0, stream,
                     W_ih, W_hh, W_lin, Wih16, Whh16, Wlin16);
  hipLaunchKernelGGL(prep_init, dim3(4096), dim3(256), 0, stream,
                     x0, h0, c0, w1, w2, bh, bc, x0hi, x0lo, h0hi, h0lo, stepc, bars);

  hipLaunchKernelGGL(lstm_persist, dim3(72), dim3(512), 0, stream,
                     x0hi, x0lo, h0hi, h0lo, c0, Wih16, Whh16, Wbig16, Wlin16,
                     bias0, bias1, b_lin, stepc, hbufH, hbufL, bh, bc, bars, outp);
}

// Round 6
// 4491.994 us; speedup vs baseline: 3.3069x; 1.0230x over previous
//
#include <hip/hip_runtime.h>
#include <math.h>

#define BB 256
#define TT 512
#define DD 256
#define HH 512
#define SS 8
#define G4H 2048
#define BH (BB*HH)          // 131072
#define OUT_BASE ((size_t)BB*TT*DD)

typedef _Float16 f16;
typedef __attribute__((ext_vector_type(8)))  _Float16 f16x8;
typedef __attribute__((ext_vector_type(16))) float    f32x16;

__device__ __forceinline__ float sigm(float x) { return 1.f / (1.f + __expf(-x)); }
__device__ __forceinline__ float ftanh(float x) {
  x = fminf(15.f, fmaxf(-15.f, x));
  float e = __expf(-2.f * x);
  return (1.f - e) / (1.f + e);
}

// ---------------- prep kernels ----------------

// W_big[n][j] = sum_d W_ih[n][d]*W_lin[d][j] + W_hh[n][j]  -> fp16 (2048x512)
__global__ __launch_bounds__(256) void prep_wbig16(
    const float* __restrict__ W_ih, const float* __restrict__ W_hh,
    const float* __restrict__ W_lin, f16* __restrict__ Wbig16)
{
  __shared__ float As[64][20];
  __shared__ float Bs[16][68];
  const int n0 = blockIdx.x * 64;
  const int j0 = blockIdx.y * 64;
  const int tid = threadIdx.x;
  const int tn = tid >> 4, tj = tid & 15;
  float acc[4][4] = {};
  for (int k0 = 0; k0 < DD; k0 += 16) {
    { int r = tid >> 2, c = (tid & 3) * 4;
      *(float4*)&As[r][c] = *(const float4*)&W_ih[(size_t)(n0 + r) * DD + k0 + c]; }
    { int r = tid >> 4, c = (tid & 15) * 4;
      *(float4*)&Bs[r][c] = *(const float4*)&W_lin[(size_t)(k0 + r) * HH + j0 + c]; }
    __syncthreads();
    #pragma unroll
    for (int k = 0; k < 16; ++k) {
      float a[4], bv[4];
      #pragma unroll
      for (int i = 0; i < 4; ++i) a[i] = As[tn*4+i][k];
      #pragma unroll
      for (int m = 0; m < 4; ++m) bv[m] = Bs[k][tj*4+m];
      #pragma unroll
      for (int i = 0; i < 4; ++i)
        #pragma unroll
        for (int m = 0; m < 4; ++m)
          acc[i][m] = fmaf(a[i], bv[m], acc[i][m]);
    }
    __syncthreads();
  }
  #pragma unroll
  for (int i = 0; i < 4; ++i) {
    int n = n0 + tn*4 + i;
    #pragma unroll
    for (int m = 0; m < 4; ++m) {
      int j = j0 + tj*4 + m;
      Wbig16[(size_t)n*HH + j] = (f16)(acc[i][m] + W_hh[(size_t)n*HH + j]);
    }
  }
}

// bias0[n] = b_ih+b_hh ; bias1[n] = bias0[n] + dot(W_ih[n,:], b_lin)
__global__ void prep_bias(const float* __restrict__ b_ih, const float* __restrict__ b_hh,
                          const float* __restrict__ W_ih, const float* __restrict__ b_lin,
                          float* __restrict__ bias0, float* __restrict__ bias1)
{
  int n = blockIdx.x * 256 + threadIdx.x;   // grid 8
  float s = b_ih[n] + b_hh[n];
  float d = 0.f;
  for (int k = 0; k < DD; ++k) d = fmaf(W_ih[(size_t)n*DD + k], b_lin[k], d);
  bias0[n] = s;
  bias1[n] = s + d;
}

// fp32 -> fp16 conversion of W_ih | W_hh | W_lin
#define NIH (G4H*DD)
#define NHH (G4H*HH)
__global__ void prep_cvtw(const float* __restrict__ W_ih, const float* __restrict__ W_hh,
                          const float* __restrict__ W_lin,
                          f16* __restrict__ Wih16, f16* __restrict__ Whh16,
                          f16* __restrict__ Wlin16)
{
  int e = blockIdx.x * 256 + threadIdx.x;   // grid 6656
  if (e < NIH) Wih16[e] = (f16)W_ih[e];
  else if (e < NIH + NHH) Whh16[e - NIH] = (f16)W_hh[e - NIH];
  else Wlin16[e - NIH - NHH] = (f16)W_lin[e - NIH - NHH];
}

// init: bh/bc from h0/c0, x0/h0 hi-lo fp16 splits, step constants, flags
__global__ void prep_init(const float* __restrict__ x0, const float* __restrict__ h0,
                          const float* __restrict__ c0,
                          const int* __restrict__ w1, const int* __restrict__ w2,
                          float* __restrict__ bh, float* __restrict__ bc,
                          f16* __restrict__ x0hi, f16* __restrict__ x0lo,
                          f16* __restrict__ h0hi, f16* __restrict__ h0lo,
                          float4* __restrict__ stepc,
                          int* __restrict__ flags)
{
  int e = blockIdx.x * 256 + threadIdx.x;   // grid 4096 -> 1048576
  int r = e & (BH - 1);
  bh[e] = h0[r];
  bc[e] = c0[r];
  if (e < BH) {
    float v = h0[e];
    f16 hi = (f16)v;
    h0hi[e] = hi;
    h0lo[e] = (f16)(v - (float)hi);
  }
  if (e < BB*DD) {
    int b = e >> 8, d = e & 255;
    float v = x0[(size_t)b*(TT*DD) + d];
    f16 hi = (f16)v;
    x0hi[e] = hi;
    x0lo[e] = (f16)(v - (float)hi);
  }
  if (e < TT) {
    float a1 = (float)w1[e], a2 = (float)w2[e];
    stepc[e] = make_float4(a1, a2, 1.f / (a1 + a2), 0.f);
  }
  if (e < 128) flags[e] = 0;
}

// ---------------- persistent main kernel ----------------

// stage 32 rows x 512 cols from u32-packed hi/lo planes (L3-coherent atomics)
// into XOR-swizzled LDS. 512 threads, 8 iters x 2 x 8B atomic loads.
__device__ __forceinline__ void stageP(const unsigned* __restrict__ srcH,
                                       const unsigned* __restrict__ srcL,
                                       f16* Ahi, f16* Alo, int tid) {
  #pragma unroll
  for (int i = 0; i < 8; ++i) {
    int lin = i * 512 + tid;            // 4096 8B chunks per plane
    int r = lin >> 7, c8 = lin & 127;
    unsigned long long vh = __hip_atomic_load(
        (const unsigned long long*)srcH + (size_t)r * 128 + c8,
        __ATOMIC_RELAXED, __HIP_MEMORY_SCOPE_AGENT);
    unsigned long long vl = __hip_atomic_load(
        (const unsigned long long*)srcL + (size_t)r * 128 + c8,
        __ATOMIC_RELAXED, __HIP_MEMORY_SCOPE_AGENT);
    int off = r * 1024 + ((((c8 >> 1) << 4)) ^ (r << 4)) + ((c8 & 1) << 3);
    *(unsigned long long*)((char*)Ahi + off) = vh;
    *(unsigned long long*)((char*)Alo + off) = vl;
  }
}

// K=512 2-pass (hi+lo) MFMA GEMM from swizzled LDS, W frags in registers
__device__ __forceinline__ f32x16 gemmA(const f16x8 (&wreg)[32],
                                        const f16* Ahi, const f16* Alo,
                                        int rbase, int kselB, int key) {
  f32x16 acc;
  #pragma unroll
  for (int i = 0; i < 16; ++i) acc[i] = 0.f;
  #pragma unroll
  for (int ks = 0; ks < 32; ++ks) {
    int off = rbase + (((ks << 5) + kselB) ^ key);
    f16x8 ah = *(const f16x8*)((const char*)Ahi + off);
    f16x8 al = *(const f16x8*)((const char*)Alo + off);
    acc = __builtin_amdgcn_mfma_f32_32x32x16_f16(ah, wreg[ks], acc, 0, 0, 0);
    acc = __builtin_amdgcn_mfma_f32_32x32x16_f16(al, wreg[ks], acc, 0, 0, 0);
  }
  return acc;
}

// 72 blocks x 512 threads. Group g = blockIdx&7 owns batch rows [32g, 32g+32).
// role = blockIdx>>3: 0..7 gates (64 j-cols x 4 gates each), 8 = out projection.
// Sync: bulletin-board flags[g][b] = completed steps, via L3-coherent atomics.
__global__ __launch_bounds__(512, 2) void lstm_persist(
    const f16* __restrict__ x0hi, const f16* __restrict__ x0lo,
    const f16* __restrict__ h0hi, const f16* __restrict__ h0lo,
    const float* __restrict__ c0,
    const f16* __restrict__ Wih16, const f16* __restrict__ Whh16,
    const f16* __restrict__ Wbig16, const f16* __restrict__ Wlin16,
    const float* __restrict__ bias0, const float* __restrict__ bias1,
    const float* __restrict__ b_lin,
    const float4* __restrict__ stepc,
    unsigned* __restrict__ hbufHp, unsigned* __restrict__ hbufLp, // 2 slots x 8g x 32 x 256 u32
    float* __restrict__ bh, float* __restrict__ bc,               // SS x B*H skip bufs
    int* __restrict__ flags,
    float* __restrict__ outp)
{
  __shared__ f16 AhiS[32 * HH];     // 32 KB, XOR-swizzled
  __shared__ f16 AloS[32 * HH];     // 32 KB
  __shared__ float gbuf[4 * 2048];  // 32 KB: [gate][32 b][64 j]

  const int tid  = threadIdx.x;
  const int lane = tid & 63;
  const int wv   = tid >> 6;            // wave 0..7
  const int grp  = blockIdx.x & 7;
  const int role = blockIdx.x >> 3;     // 0..8
  const bool isG = role < 8;
  const int b0   = grp * 32;

  const int row   = lane & 31;
  const int ksel8 = (lane >> 5) * 8;
  const int kselB = ksel8 * 2;
  const int rbase = row * 1024;
  const int key   = row << 4;

  int* gflag = flags + grp * 16;

  // ---- persistent W fragments (K=512 -> 32 frags = 128 VGPR) ----
  int wrow;
  const f16* wbase;
  if (isG) {
    wrow  = (wv & 3) * 512 + role * 64 + (wv >> 2) * 32 + row;
    wbase = Wbig16 + (size_t)wrow * HH;
  } else {
    wrow  = wv * 32 + row;              // d-column
    wbase = Wlin16 + (size_t)wrow * HH;
  }
  f16x8 wreg[32];
  #pragma unroll
  for (int ks = 0; ks < 32; ++ks)
    wreg[ks] = *(const f16x8*)(wbase + ks * 16 + ksel8);

  const float bld = isG ? 0.f : b_lin[wrow];

  // ---- gates per-thread epilogue constants (registers) ----
  int   eidx[4], jv[4];
  float bI[4], bF[4], bG[4], bO[4], creg[4];
  if (isG) {
    #pragma unroll
    for (int i = 0; i < 4; ++i) {
      int c = i * 512 + tid;
      int bl = c >> 6, jl = c & 63;
      int j = role * 64 + jl;
      jv[i]   = j;
      eidx[i] = (b0 + bl) * HH + j;
      bI[i] = bias1[j];          bF[i] = bias1[512 + j];
      bG[i] = bias1[1024 + j];   bO[i] = bias1[1536 + j];
      creg[i] = c0[eidx[i]];
    }
  }

  for (int t = 0; t <= TT; ++t) {
    if (isG && t == TT) break;          // gates finished at t = TT-1

    if (t > 0) {
      // wait until all 9 blocks of this group completed step t-1
      if (tid < 9)
        while (__hip_atomic_load(&gflag[tid], __ATOMIC_RELAXED,
                                 __HIP_MEMORY_SCOPE_AGENT) < t)
          __builtin_amdgcn_s_sleep(1);
      __syncthreads();
    }

    if (isG) {
      // prefetch step constants + skip-buffer reads (hidden under GEMM)
      const float4 sc = stepc[t];
      const int pos = t & (SS - 1);
      float shv[4], scv[4];
      #pragma unroll
      for (int i = 0; i < 4; ++i) {
        int bx = pos * BH + eidx[i];
        shv[i] = bh[bx];
        scv[i] = bc[bx];
      }

      f32x16 acc;
      if (t == 0) {
        #pragma unroll
        for (int i = 0; i < 16; ++i) acc[i] = 0.f;
        const f16* arh = x0hi + (size_t)(b0 + row) * DD;
        const f16* arl = x0lo + (size_t)(b0 + row) * DD;
        const f16* w1p = Wih16 + (size_t)wrow * DD;
        #pragma unroll
        for (int ks = 0; ks < 16; ++ks) {       // K=256: x0 @ W_ih^T
          int ko = ks * 16 + ksel8;
          f16x8 w = *(const f16x8*)(w1p + ko);
          acc = __builtin_amdgcn_mfma_f32_32x32x16_f16(*(const f16x8*)(arh + ko), w, acc, 0,0,0);
          acc = __builtin_amdgcn_mfma_f32_32x32x16_f16(*(const f16x8*)(arl + ko), w, acc, 0,0,0);
        }
        const f16* brh = h0hi + (size_t)(b0 + row) * HH;
        const f16* brl = h0lo + (size_t)(b0 + row) * HH;
        const f16* w2p = Whh16 + (size_t)wrow * HH;
        #pragma unroll
        for (int ks = 0; ks < 32; ++ks) {       // K=512: h0 @ W_hh^T
          int ko = ks * 16 + ksel8;
          f16x8 w = *(const f16x8*)(w2p + ko);
          acc = __builtin_amdgcn_mfma_f32_32x32x16_f16(*(const f16x8*)(brh + ko), w, acc, 0,0,0);
          acc = __builtin_amdgcn_mfma_f32_32x32x16_f16(*(const f16x8*)(brl + ko), w, acc, 0,0,0);
        }
      } else {
        const int slotR = (t - 1) & 1;
        stageP(hbufHp + (size_t)(slotR * 8 + grp) * 8192,
               hbufLp + (size_t)(slotR * 8 + grp) * 8192, AhiS, AloS, tid);
        __syncthreads();
        acc = gemmA(wreg, AhiS, AloS, rbase, kselB, key);
      }

      // reshuffle acc -> gbuf [gate][b][j]
      {
        const int col = lane & 31;
        const int g4 = wv & 3, jh = wv >> 2;
        #pragma unroll
        for (int rg = 0; rg < 16; ++rg) {
          int m = (rg & 3) + ((rg >> 2) << 3) + ((lane >> 5) << 2);
          gbuf[g4 * 2048 + m * 64 + jh * 32 + col] = acc[rg];
        }
      }
      __syncthreads();

      // fused elementwise LSTM + skip combine
      const float a1 = sc.x, a2 = sc.y, nrm = sc.z;
      const int slotW = t & 1;
      const size_t pbase = (size_t)(slotW * 8 + grp) * 8192;
      #pragma unroll
      for (int i = 0; i < 4; ++i) {
        int c = i * 512 + tid;
        int bl = c >> 6;
        float baI = bI[i], baF = bF[i], baG = bG[i], baO = bO[i];
        if (t == 0) {
          baI = bias0[jv[i]];        baF = bias0[512 + jv[i]];
          baG = bias0[1024 + jv[i]]; baO = bias0[1536 + jv[i]];
        }
        float pi = gbuf[c]        + baI;
        float pf = gbuf[2048 + c] + baF;
        float pg = gbuf[4096 + c] + baG;
        float po = gbuf[6144 + c] + baO;
        float i_ = sigm(pi), f_ = sigm(pf), o_ = sigm(po), g_ = ftanh(pg);
        float cnew = fmaf(f_, creg[i], i_ * g_);
        float hnew = o_ * ftanh(cnew);
        float ch = (a1 * hnew + a2 * ftanh(shv[i])) * nrm;
        float cc = (a1 * cnew + a2 * ftanh(scv[i])) * nrm;
        creg[i] = cc;
        int bx = pos * BH + eidx[i];
        bh[bx] = hnew;                       // block-private: plain cached stores
        bc[bx] = cnew;
        // pack (hi,lo) as u32; pair with neighbor lane; publish via L3 atomics
        f16 chh = (f16)ch;
        f16 chl = (f16)(ch - (float)chh);
        unsigned packed = (unsigned)*(unsigned short*)&chh |
                          ((unsigned)*(unsigned short*)&chl << 16);
        unsigned part = (unsigned)__shfl_xor((int)packed, 1);
        unsigned sval;
        unsigned* plane;
        if ((tid & 1) == 0) { sval = (packed & 0xffffu) | (part << 16); plane = hbufHp; }
        else                { sval = (part >> 16) | (packed & 0xffff0000u); plane = hbufLp; }
        __hip_atomic_store(&plane[pbase + bl * 256 + (jv[i] >> 1)], sval,
                           __ATOMIC_RELAXED, __HIP_MEMORY_SCOPE_AGENT);
        if (t == TT - 1) {
          __builtin_nontemporal_store(ch, &outp[OUT_BASE + eidx[i]]);        // h_fin
          __builtin_nontemporal_store(cc, &outp[OUT_BASE + BH + eidx[i]]);   // c_fin
        }
      }
    } else if (t >= 1) {
      // out[t-1] = comb_h[t-1] @ W_lin^T + b_lin
      const int slotR = (t - 1) & 1;
      stageP(hbufHp + (size_t)(slotR * 8 + grp) * 8192,
             hbufLp + (size_t)(slotR * 8 + grp) * 8192, AhiS, AloS, tid);
      __syncthreads();
      f32x16 acc = gemmA(wreg, AhiS, AloS, rbase, kselB, key);
      const size_t tbase = (size_t)(t - 1) * DD + wrow;
      #pragma unroll
      for (int rg = 0; rg < 16; ++rg) {
        int m = (rg & 3) + ((rg >> 2) << 3) + ((lane >> 5) << 2);
        __builtin_nontemporal_store(acc[rg] + bld,
                                    &outp[(size_t)(b0 + m) * (TT*DD) + tbase]);
      }
      __syncthreads();   // stores drained (each thread waits vmcnt pre-barrier)
    }

    // publish completion of step t (syncthreads above/below drains all threads' stores)
    __syncthreads();
    if (tid == 0 && t < TT)
      __hip_atomic_store(&gflag[role], t + 1, __ATOMIC_RELAXED,
                         __HIP_MEMORY_SCOPE_AGENT);
  }
}

// ---------------- host launch ----------------

extern "C" void kernel_launch(void* const* d_in, const int* in_sizes, int n_in,
                              void* d_out, int out_size, void* d_ws, size_t ws_size,
                              hipStream_t stream)
{
  const float* x0    = (const float*)d_in[0];
  const float* h0    = (const float*)d_in[1];
  const float* c0    = (const float*)d_in[2];
  const float* W_ih  = (const float*)d_in[3];
  const float* W_hh  = (const float*)d_in[4];
  const float* b_ih  = (const float*)d_in[5];
  const float* b_hh  = (const float*)d_in[6];
  const float* W_lin = (const float*)d_in[7];
  const float* b_lin = (const float*)d_in[8];
  const int*   w1    = (const int*)d_in[9];
  const int*   w2    = (const int*)d_in[10];

  char* p = (char*)d_ws;
  f16* Wbig16 = (f16*)p;            p += (size_t)G4H*HH*2;
  f16* Wih16  = (f16*)p;            p += (size_t)G4H*DD*2;
  f16* Whh16  = (f16*)p;            p += (size_t)G4H*HH*2;
  f16* Wlin16 = (f16*)p;            p += (size_t)DD*HH*2;
  f16* x0hi   = (f16*)p;            p += (size_t)BB*DD*2;
  f16* x0lo   = (f16*)p;            p += (size_t)BB*DD*2;
  f16* h0hi   = (f16*)p;            p += (size_t)BH*2;
  f16* h0lo   = (f16*)p;            p += (size_t)BH*2;
  unsigned* hbufHp = (unsigned*)p;  p += (size_t)2*8*8192*4;   // 512 KB
  unsigned* hbufLp = (unsigned*)p;  p += (size_t)2*8*8192*4;   // 512 KB
  float* bh   = (float*)p;          p += (size_t)SS*BH*4;
  float* bc   = (float*)p;          p += (size_t)SS*BH*4;
  float* bias0= (float*)p;          p += G4H*4;
  float* bias1= (float*)p;          p += G4H*4;
  float4* stepc = (float4*)p;       p += (size_t)TT*16;
  int*  flags = (int*)p;            p += 128*4;
  float* outp = (float*)d_out;

  hipLaunchKernelGGL(prep_wbig16, dim3(32, 8), dim3(256), 0, stream,
                     W_ih, W_hh, W_lin, Wbig16);
  hipLaunchKernelGGL(prep_bias, dim3(8), dim3(256), 0, stream,
                     b_ih, b_hh, W_ih, b_lin, bias0, bias1);
  hipLaunchKernelGGL(prep_cvtw, dim3(6656), dim3(256), 0, stream,
                     W_ih, W_hh, W_lin, Wih16, Whh16, Wlin16);
  hipLaunchKernelGGL(prep_init, dim3(4096), dim3(256), 0, stream,
                     x0, h0, c0, w1, w2, bh, bc, x0hi, x0lo, h0hi, h0lo, stepc, flags);

  hipLaunchKernelGGL(lstm_persist, dim3(72), dim3(512), 0, stream,
                     x0hi, x0lo, h0hi, h0lo, c0, Wih16, Whh16, Wbig16, Wlin16,
                     bias0, bias1, b_lin, stepc, hbufHp, hbufLp, bh, bc, flags, outp);
}